// Round 12
// baseline (482.823 us; speedup 1.0000x reference)
//
#include <hip/hip_runtime.h>

typedef __attribute__((ext_vector_type(8))) short short8;
typedef __attribute__((ext_vector_type(4))) short short4v;
typedef __attribute__((ext_vector_type(4))) float float4v;
typedef __attribute__((ext_vector_type(4))) unsigned uint4v;
typedef __attribute__((ext_vector_type(2))) unsigned uint2v;
typedef __attribute__((ext_vector_type(4))) _Float16 half4;

constexpr int T  = 2048;
constexpr int DM = 256;
constexpr int DK = 32;

__device__ inline short f2bf(float f) {
  unsigned u = __builtin_bit_cast(unsigned, f);
  u += 0x7fff + ((u >> 16) & 1);            // RNE
  return (short)(u >> 16);
}

__device__ inline unsigned pk2(float a, float b) {
#if __has_builtin(__builtin_amdgcn_cvt_pk_bf16_f32)
  auto r = __builtin_amdgcn_cvt_pk_bf16_f32(a, b);
  return __builtin_bit_cast(unsigned, r);
#else
  unsigned ua = __builtin_bit_cast(unsigned, a);
  ua = (ua + 0x7fff + ((ua >> 16) & 1)) >> 16;
  unsigned ub = __builtin_bit_cast(unsigned, b);
  ub = (ub + 0x7fff + ((ub >> 16) & 1)) >> 16;
  return ua | (ub << 16);
#endif
}

__device__ inline float fexp2(float x) {
#if __has_builtin(__builtin_amdgcn_exp2f)
  return __builtin_amdgcn_exp2f(x);
#else
  return exp2f(x);
#endif
}

__device__ inline short8 load8_bf(const float* __restrict__ p) {
  float4v a = *(const float4v*)p;
  float4v b = *(const float4v*)(p + 4);
  uint4v u;
  u[0] = pk2(a[0], a[1]); u[1] = pk2(a[2], a[3]);
  u[2] = pk2(b[0], b[1]); u[3] = pk2(b[2], b[3]);
  return __builtin_bit_cast(short8, u);
}

// ---------------------------------------------------------------------------
// Hand-rolled grid barrier. SAFE ONLY because grid=512 and launch_bounds
// (256,2) + 71,680B LDS guarantee exactly 2 blocks/CU x 256 CUs co-resident.
// Device-scope atomics (default on HIP, m20); threadfence for cross-XCD vis.
// cnt/flag zeroed by hipMemsetAsync before launch.
// ---------------------------------------------------------------------------
__device__ inline void grid_barrier(unsigned* cnt, unsigned* flag) {
  __syncthreads();                      // drains vmcnt: block's writes issued
  if (threadIdx.x == 0) {
    __threadfence();                    // flush to device scope
    unsigned a = atomicAdd(cnt, 1u);
    if (a == 511u) {
      atomicExch(flag, 1u);
    } else {
      while (atomicAdd(flag, 0u) == 0u) {
#if __has_builtin(__builtin_amdgcn_s_sleep)
        __builtin_amdgcn_s_sleep(8);
#endif
      }
    }
    __threadfence();                    // acquire: invalidate stale caches
  }
  __syncthreads();
}

// ===== phase bodies — LDS passed as TYPED ARRAY REFERENCES only (r10 pitfall:
// char* LDS loses the address space -> flat addressing -> 400MB spill traffic).

// K/Q projection: 128x64 tile, fp32 in -> bf16 out, K=N=256.
__device__ inline void proj_body(const float* __restrict__ A,
                                 const float* __restrict__ Bw,
                                 const float* __restrict__ bias,
                                 short* __restrict__ C, float oscale,
                                 int bx, int by,
                                 short (&As)[128][40], short (&Bs)[128][40]) {
  const int tid  = threadIdx.x;
  const int wave = tid >> 6, lane = tid & 63;
  const int l15  = lane & 15, quad = lane >> 4;
  const int wm   = (wave & 1) * 64, wn = (wave >> 1) * 32;
  const long Abase = (long)bx * 128;
  const long Bbase = (long)by * 64;

  float4v acc[4][2];
  for (int i = 0; i < 4; i++)
    for (int j = 0; j < 2; j++)
      for (int r = 0; r < 4; r++) acc[i][j][r] = 0.f;

  const int srow = tid >> 2;
  const int sc8  = (tid & 3) * 8;

  for (int k0 = 0; k0 < 256; k0 += 32) {
    __syncthreads();
    for (int i = 0; i < 2; i++) {
      int row = srow + i * 64;
      *(short8*)&As[row][sc8] = load8_bf(A + (Abase + row) * 256 + k0 + sc8);
    }
    *(short8*)&Bs[srow][sc8] = load8_bf(Bw + (Bbase + srow) * 256 + k0 + sc8);
    __syncthreads();
    short8 af[4], bfr[2];
    for (int ms = 0; ms < 4; ms++) af[ms]  = *(const short8*)&As[wm + ms*16 + l15][quad*8];
    for (int ns = 0; ns < 2; ns++) bfr[ns] = *(const short8*)&Bs[wn + ns*16 + l15][quad*8];
    for (int ms = 0; ms < 4; ms++)
      for (int ns = 0; ns < 2; ns++)
        acc[ms][ns] = __builtin_amdgcn_mfma_f32_16x16x32_bf16(af[ms], bfr[ns], acc[ms][ns], 0, 0, 0);
  }

  for (int ms = 0; ms < 4; ms++) {
    int rowl = wm + ms*16 + quad*4;
    for (int ns = 0; ns < 2; ns++) {
      int col = (int)Bbase + wn + ns*16 + l15;
      float bv = bias[col];
      for (int r = 0; r < 4; r++) {
        long row = Abase + rowl + r;
        C[row * 256 + col] = f2bf((acc[ms][ns][r] + bv) * oscale);
      }
    }
  }
}

// Wfused[h][n][k] = sum_d WO_w[n, d*8+h] * WV_w[h*256+d, k], bf16 out.
__device__ inline void wf_body(const float* __restrict__ WO_w,
                               const float* __restrict__ WV_w,
                               short* __restrict__ Wf,
                               int h, int bx, int by,
                               short (&As)[128][40], short (&Bs)[128][40]) {
  const int tid  = threadIdx.x;
  const int wave = tid >> 6, lane = tid & 63;
  const int l15  = lane & 15, quad = lane >> 4;
  const int wm   = (wave & 1) * 64, wn = (wave >> 1) * 32;
  const int srow = tid >> 2, sc8 = (tid & 3) * 8;

  float4v acc[4][2];
  for (int i = 0; i < 4; i++)
    for (int j = 0; j < 2; j++)
      for (int r = 0; r < 4; r++) acc[i][j][r] = 0.f;

  for (int d0 = 0; d0 < 256; d0 += 32) {
    __syncthreads();
    for (int i = 0; i < 2; i++) {
      int row = srow + i * 64;
      for (int j = 0; j < 8; j++)
        As[row][sc8 + j] = f2bf(WO_w[(bx*128 + row) * 2048 + (d0 + sc8 + j) * 8 + h]);
    }
    for (int j = 0; j < 8; j++)
      Bs[srow][sc8 + j] = f2bf(WV_w[((h*256) + d0 + sc8 + j) * 256 + by*64 + srow]);
    __syncthreads();
    short8 af[4], bfr[2];
    for (int ms = 0; ms < 4; ms++) af[ms]  = *(const short8*)&As[wm + ms*16 + l15][quad*8];
    for (int ns = 0; ns < 2; ns++) bfr[ns] = *(const short8*)&Bs[wn + ns*16 + l15][quad*8];
    for (int ms = 0; ms < 4; ms++)
      for (int ns = 0; ns < 2; ns++)
        acc[ms][ns] = __builtin_amdgcn_mfma_f32_16x16x32_bf16(af[ms], bfr[ns], acc[ms][ns], 0, 0, 0);
  }
  for (int ms = 0; ms < 4; ms++) {
    int m = bx*128 + wm + ms*16 + quad*4;
    for (int ns = 0; ns < 2; ns++) {
      int col = by*64 + wn + ns*16 + l15;
      for (int r = 0; r < 4; r++)
        Wf[((long)h*256 + m + r) * 256 + col] = f2bf(acc[ms][ns][r]);
    }
  }
}

// Ut[b][h*256+n][s] = sum_k Wf[h*256+n][k]*value_x[b*2048+s][k] + cbias[.]
__device__ inline void ut_body(const short* __restrict__ Wf,
                               const float* __restrict__ Bw,
                               const float* __restrict__ cbias,
                               short* __restrict__ Ut,
                               int bx, int by,
                               short (&As)[128][40], short (&Bs)[128][40]) {
  const int tid  = threadIdx.x;
  const int wave = tid >> 6, lane = tid & 63;
  const int l15  = lane & 15, quad = lane >> 4;
  const int wm   = (wave & 1) * 64, wn = (wave >> 1) * 64;
  const long Abase = (long)bx * 128;
  const long Bbase = (long)by * 128;

  float4v acc[4][4];
  for (int i = 0; i < 4; i++)
    for (int j = 0; j < 4; j++)
      for (int r = 0; r < 4; r++) acc[i][j][r] = 0.f;

  const int srow = tid >> 2;
  const int sc8  = (tid & 3) * 8;

  for (int k0 = 0; k0 < 256; k0 += 32) {
    __syncthreads();
    for (int i = 0; i < 2; i++) {
      int row = srow + i * 64;
      *(short8*)&As[row][sc8] = *(const short8*)(Wf + (Abase + row) * 256 + k0 + sc8);
      *(short8*)&Bs[row][sc8] = load8_bf(Bw + (Bbase + row) * 256 + k0 + sc8);
    }
    __syncthreads();
    short8 af[4], bfr[4];
    for (int ms = 0; ms < 4; ms++) af[ms]  = *(const short8*)&As[wm + ms*16 + l15][quad*8];
    for (int ns = 0; ns < 4; ns++) bfr[ns] = *(const short8*)&Bs[wn + ns*16 + l15][quad*8];
    for (int ms = 0; ms < 4; ms++)
      for (int ns = 0; ns < 4; ns++)
        acc[ms][ns] = __builtin_amdgcn_mfma_f32_16x16x32_bf16(af[ms], bfr[ns], acc[ms][ns], 0, 0, 0);
  }

  for (int ms = 0; ms < 4; ms++) {
    int rowl = wm + ms*16 + quad*4;
    for (int ns = 0; ns < 4; ns++) {
      int col = (int)Bbase + wn + ns*16 + l15;
      int bidx = col >> 11, scol = col & 2047;
      for (int r = 0; r < 4; r++) {
        long m = Abase + rowl + r;
        Ut[((long)bidx * 2048 + m) * 2048 + scol] = f2bf(acc[ms][ns][r] + cbias[m]);
      }
    }
  }
}

// Fused attention (r9 structure, measured 122.8us) -> fp16 per-head partials.
__device__ inline void attn_body(const short* __restrict__ Kp,
                                 const short* __restrict__ Qp,
                                 const short* __restrict__ Ut,
                                 _Float16* __restrict__ partial, int L,
                                 short (&Pt)[2][128][136], float (&psum)[128][4]) {
  const int tid  = threadIdx.x;
  const int wave = tid >> 6, lane = tid & 63;
  const int l15  = lane & 15, quad = lane >> 4;

  const int h  = L & 7;
  const int b  = (L >> 3) & 3;
  const int q0 = (L >> 5) * 128;

  const short* Kbh = Kp + (long)b * T * DM + h * DK;
  const short* Qbh = Qp + (long)b * T * DM + h * DK;
  const short* Ubh = Ut + ((long)b * 2048 + h * 256) * 2048;

  float4v acc[4][8];
  for (int i = 0; i < 4; i++)
    for (int j = 0; j < 8; j++)
      for (int r = 0; r < 4; r++) acc[i][j][r] = 0.f;

  float ps[8];
  for (int i = 0; i < 8; i++) ps[i] = 0.f;

  short8 qf[8];
  for (int qs = 0; qs < 8; qs++)
    qf[qs] = *(const short8*)(Qbh + (long)(q0 + qs*16 + l15) * DM + quad*8);

  auto computeSt = [&](int s0, int buf) {
    for (int ss = 0; ss < 2; ss++) {
      short8 kf = *(const short8*)(Kbh + (long)(s0 + wave*32 + ss*16 + l15) * DM + quad*8);
      for (int qs = 0; qs < 8; qs++) {
        float4v z = {0.f, 0.f, 0.f, 0.f};
        float4v st = __builtin_amdgcn_mfma_f32_16x16x32_bf16(kf, qf[qs], z, 0, 0, 0);
        float p0 = fexp2(st[0]), p1 = fexp2(st[1]);
        float p2 = fexp2(st[2]), p3 = fexp2(st[3]);
        ps[qs] += (p0 + p1) + (p2 + p3);
        uint2v pb; pb[0] = pk2(p0, p1); pb[1] = pk2(p2, p3);
        *(uint2v*)&Pt[buf][qs*16 + l15][wave*32 + ss*16 + quad*4] = pb;
      }
    }
  };

  computeSt(0, 0);

  for (int it = 0; it < T / 128; it++) {
    const int buf = it & 1;
    const int s0  = it * 128;
    __syncthreads();
    if (it < T / 128 - 1) computeSt(s0 + 128, buf ^ 1);
    for (int ks = 0; ks < 4; ks++) {
      short8 pf[8];
      for (int ns = 0; ns < 8; ns++)
        pf[ns] = *(const short8*)&Pt[buf][ns*16 + l15][ks*32 + quad*8];
      for (int ms = 0; ms < 4; ms++) {
        short8 vf = *(const short8*)(Ubh + (long)(wave*64 + ms*16 + l15) * 2048
                                     + s0 + ks*32 + quad*8);
        for (int ns = 0; ns < 8; ns++)
          acc[ms][ns] = __builtin_amdgcn_mfma_f32_16x16x32_bf16(vf, pf[ns], acc[ms][ns], 0, 0, 0);
      }
    }
  }

  for (int qs = 0; qs < 8; qs++) {
    ps[qs] += __shfl_xor(ps[qs], 16, 64);
    ps[qs] += __shfl_xor(ps[qs], 32, 64);
  }
  if (lane < 16)
    for (int qs = 0; qs < 8; qs++) psum[qs*16 + lane][wave] = ps[qs];
  __syncthreads();

  for (int ns = 0; ns < 8; ns++) {
    float4v sv = *(const float4v*)&psum[ns*16 + l15][0];
    float rl = 1.0f / (sv[0] + sv[1] + sv[2] + sv[3]);
    long pbase = ((long)h * 8192 + b * T + q0 + ns*16 + l15) * 256;
    for (int ms = 0; ms < 4; ms++) {
      int ncol = wave*64 + ms*16 + quad*4;
      half4 hv;
      for (int r = 0; r < 4; r++) hv[r] = (_Float16)(acc[ms][ns][r] * rl);
      *(half4*)(partial + pbase + ncol) = hv;
    }
  }
}

// ---------------------------------------------------------------------------
// mega: the whole pipeline in ONE 512-block dispatch (2 blocks/CU, fully
// co-resident -> hand-rolled grid barriers are safe).
//  phase0: K/Q proj (512) + Wf (blocks 0-63) + cbias (blocks 64-191)
//  phase1: Ut (1024 jobs, 2/block)
//  phase2: attention (512 jobs)
//  phase3: reduce partials + WO_b -> out
// ---------------------------------------------------------------------------
__global__ __launch_bounds__(256, 2)
void mega(const float* __restrict__ key_x, const float* __restrict__ query_x,
          const float* __restrict__ value_x,
          const float* __restrict__ WK_w, const float* __restrict__ WK_b,
          const float* __restrict__ WQ_w, const float* __restrict__ WQ_b,
          const float* __restrict__ WV_w, const float* __restrict__ WV_b,
          const float* __restrict__ WO_w, const float* __restrict__ WO_b,
          short* __restrict__ Kp, short* __restrict__ Qp,
          short* __restrict__ Ut, short* __restrict__ Wf,
          float* __restrict__ cbias, _Float16* __restrict__ part,
          float* __restrict__ outp, unsigned* __restrict__ bar) {
  union SMem {
    struct { short As[128][40]; short Bs[128][40]; } g;     // 20480 B
    struct { short Pt[2][128][136]; float psum[128][4]; } a; // 71680 B
    float cb[16][17];
  };
  __shared__ __align__(16) SMem sm;

  const int gb  = blockIdx.x;
  const int tid = threadIdx.x;

  // ---- phase 0
  if (gb < 256)
    proj_body(key_x, WK_w, WK_b, Kp, 1.0f, gb & 63, gb >> 6, sm.g.As, sm.g.Bs);
  else
    proj_body(query_x, WQ_w, WQ_b, Qp, 1.44269504f,
              (gb - 256) & 63, (gb - 256) >> 6, sm.g.As, sm.g.Bs);
  __syncthreads();
  if (gb < 64) {
    wf_body(WO_w, WV_w, Wf, gb >> 3, (gb >> 2) & 1, gb & 3, sm.g.As, sm.g.Bs);
  } else if (gb < 192) {
    const int idx = gb - 64;
    const int h = idx >> 4, ng = idx & 15;
    const int ni = tid & 15, di = tid >> 4;
    const int n = ng * 16 + ni;
    float acc = 0.f;
    for (int j = 0; j < 16; j++) {
      int d = di * 16 + j;
      acc += WV_b[h*256 + d] * WO_w[n * 2048 + d*8 + h];
    }
    sm.cb[ni][di] = acc;
    __syncthreads();
    if (tid < 16) {
      float s = 0.f;
      for (int d2 = 0; d2 < 16; d2++) s += sm.cb[tid][d2];
      cbias[h*256 + ng*16 + tid] = s;
    }
  }
  grid_barrier(bar + 0, bar + 1);

  // ---- phase 1: Ut
  for (int jj = gb; jj < 1024; jj += 512)
    ut_body(Wf, value_x, cbias, Ut, jj & 15, jj >> 4, sm.g.As, sm.g.Bs);
  grid_barrier(bar + 2, bar + 3);

  // ---- phase 2: attention
  attn_body(Kp, Qp, Ut, part, gb, sm.a.Pt, sm.a.psum);
  grid_barrier(bar + 4, bar + 5);

  // ---- phase 3: reduce
  const long HP = 8192L * 256;
  for (int it = 0; it < 4; it++) {
    long i4 = ((long)gb * 1024 + it * 256 + tid) * 4;
    float4v o = *(const float4v*)(WO_b + (i4 & 255));
    for (int h = 0; h < 8; h++) {
      half4 hv = *(const half4*)(part + h * HP + i4);
      for (int r = 0; r < 4; r++) o[r] += (float)hv[r];
    }
    *(float4v*)(outp + i4) = o;
  }
}

// ---------------------------------------------------------------------------
extern "C" void kernel_launch(void* const* d_in, const int* in_sizes, int n_in,
                              void* d_out, int out_size, void* d_ws, size_t ws_size,
                              hipStream_t stream) {
  const float* key_x   = (const float*)d_in[0];
  const float* query_x = (const float*)d_in[1];
  const float* value_x = (const float*)d_in[2];
  const float* WK_w = (const float*)d_in[4];
  const float* WK_b = (const float*)d_in[5];
  const float* WQ_w = (const float*)d_in[6];
  const float* WQ_b = (const float*)d_in[7];
  const float* WV_w = (const float*)d_in[8];
  const float* WV_b = (const float*)d_in[9];
  const float* WO_w = (const float*)d_in[10];
  const float* WO_b = (const float*)d_in[11];

  char* ws = (char*)d_ws;
  short*     Kp    = (short*)(ws);                  //  4 MB  [8192][256] bf16
  short*     Qp    = (short*)(ws + (4u  << 20));    //  4 MB  (x log2e)
  short*     Ut    = (short*)(ws + (8u  << 20));    // 32 MB  [4][2048][2048] bf16
  short*     Wf    = (short*)(ws + (40u << 20));    //  1 MB  [8*256][256] bf16
  float*     cbias = (float*)(ws + (41u << 20));    //  8 KB  [8][256] fp32
  unsigned*  bar   = (unsigned*)(ws + (41u << 20) + (64u << 10)); // 64 B counters
  _Float16*  part  = (_Float16*)(ws + (42u << 20)); // 32 MB  [8][8192][256] fp16
  float*     outp  = (float*)d_out;

  hipMemsetAsync(bar, 0, 64, stream);   // zero barrier counters (ws is poisoned)
  mega<<<512, 256, 0, stream>>>(key_x, query_x, value_x,
                                WK_w, WK_b, WQ_w, WQ_b, WV_w, WV_b,
                                WO_w, WO_b, Kp, Qp, Ut, Wf, cbias,
                                part, outp, bar);
}

// Round 13
// 298.671 us; speedup vs baseline: 1.6166x; 1.6166x over previous
//
#include <hip/hip_runtime.h>

typedef __attribute__((ext_vector_type(8))) short short8;
typedef __attribute__((ext_vector_type(4))) short short4v;
typedef __attribute__((ext_vector_type(4))) float float4v;
typedef __attribute__((ext_vector_type(4))) unsigned uint4v;
typedef __attribute__((ext_vector_type(2))) unsigned uint2v;
typedef __attribute__((ext_vector_type(4))) _Float16 half4;

constexpr int T  = 2048;
constexpr int DM = 256;
constexpr int DK = 32;

__device__ inline short f2bf(float f) {
  unsigned u = __builtin_bit_cast(unsigned, f);
  u += 0x7fff + ((u >> 16) & 1);            // RNE
  return (short)(u >> 16);
}

__device__ inline unsigned pk2(float a, float b) {
#if __has_builtin(__builtin_amdgcn_cvt_pk_bf16_f32)
  auto r = __builtin_amdgcn_cvt_pk_bf16_f32(a, b);
  return __builtin_bit_cast(unsigned, r);
#else
  unsigned ua = __builtin_bit_cast(unsigned, a);
  ua = (ua + 0x7fff + ((ua >> 16) & 1)) >> 16;
  unsigned ub = __builtin_bit_cast(unsigned, b);
  ub = (ub + 0x7fff + ((ub >> 16) & 1)) >> 16;
  return ua | (ub << 16);
#endif
}

__device__ inline float fexp2(float x) {
#if __has_builtin(__builtin_amdgcn_exp2f)
  return __builtin_amdgcn_exp2f(x);
#else
  return exp2f(x);
#endif
}

// ---------------------------------------------------------------------------
// prep (976 blocks): one-time fp32 -> bf16 conversions + tiny weight algebra.
//  [0,256)   key_x   -> Kb   (2M elems, 8192/block)
//  [256,512) query_x -> Qb
//  [512,768) value_x -> Vb
//  [768,776) WK_w -> WKb   [776,784) WQ_w -> WQb
//  [784,848) Wfused[h][n][k] = sum_d WO_w[n,d*8+h]*WV_w[h*256+d,k]  (bf16)
//  [848,976) cbias[h][n]    = sum_d WV_b[h*256+d]*WO_w[n,d*8+h]     (fp32)
// ---------------------------------------------------------------------------
__device__ inline void conv_block(const float* __restrict__ src,
                                  short* __restrict__ dst, int blk) {
  const int tid = threadIdx.x;
  for (int j = 0; j < 8; j++) {
    int idx = blk * 8192 + j * 1024 + tid * 4;
    float4v v = *(const float4v*)(src + idx);
    uint2v u; u[0] = pk2(v[0], v[1]); u[1] = pk2(v[2], v[3]);
    *(uint2v*)(dst + idx) = u;
  }
}

__global__ __launch_bounds__(256)
void prep(const float* __restrict__ key_x, const float* __restrict__ query_x,
          const float* __restrict__ value_x,
          const float* __restrict__ WK_w, const float* __restrict__ WQ_w,
          const float* __restrict__ WV_w, const float* __restrict__ WV_b,
          const float* __restrict__ WO_w,
          short* __restrict__ Kb, short* __restrict__ Qb, short* __restrict__ Vb,
          short* __restrict__ WKb, short* __restrict__ WQb,
          short* __restrict__ Wf, float* __restrict__ cbias) {
  __shared__ __align__(16) short As[128][40];
  __shared__ __align__(16) short Bs[128][40];
  __shared__ float cb_s[16][17];
  const int gb  = blockIdx.x;
  const int tid = threadIdx.x;

  if (gb < 256) {
    conv_block(key_x, Kb, gb);
  } else if (gb < 512) {
    conv_block(query_x, Qb, gb - 256);
  } else if (gb < 768) {
    conv_block(value_x, Vb, gb - 512);
  } else if (gb < 776) {
    conv_block(WK_w, WKb, gb - 768);
  } else if (gb < 784) {
    conv_block(WQ_w, WQb, gb - 776);
  } else if (gb < 848) {
    // Wfused: per-head NN-GEMM [256n x 256d] x [256d x 256k]
    const int w  = gb - 784;
    const int h  = w >> 3;
    const int bx = (w >> 2) & 1;
    const int by = w & 3;
    const int wave = tid >> 6, lane = tid & 63;
    const int l15  = lane & 15, quad = lane >> 4;
    const int wm   = (wave & 1) * 64, wn = (wave >> 1) * 32;
    const int srow = tid >> 2, sc8 = (tid & 3) * 8;

    float4v acc[4][2];
    for (int i = 0; i < 4; i++)
      for (int j = 0; j < 2; j++)
        for (int r = 0; r < 4; r++) acc[i][j][r] = 0.f;

    for (int d0 = 0; d0 < 256; d0 += 32) {
      __syncthreads();
      for (int i = 0; i < 2; i++) {
        int row = srow + i * 64;
        for (int j = 0; j < 8; j++)
          As[row][sc8 + j] = f2bf(WO_w[(bx*128 + row) * 2048 + (d0 + sc8 + j) * 8 + h]);
      }
      for (int j = 0; j < 8; j++)
        Bs[srow][sc8 + j] = f2bf(WV_w[((h*256) + d0 + sc8 + j) * 256 + by*64 + srow]);
      __syncthreads();
      short8 af[4], bfr[2];
      for (int ms = 0; ms < 4; ms++) af[ms]  = *(const short8*)&As[wm + ms*16 + l15][quad*8];
      for (int ns = 0; ns < 2; ns++) bfr[ns] = *(const short8*)&Bs[wn + ns*16 + l15][quad*8];
      for (int ms = 0; ms < 4; ms++)
        for (int ns = 0; ns < 2; ns++)
          acc[ms][ns] = __builtin_amdgcn_mfma_f32_16x16x32_bf16(af[ms], bfr[ns], acc[ms][ns], 0, 0, 0);
    }
    for (int ms = 0; ms < 4; ms++) {
      int m = bx*128 + wm + ms*16 + quad*4;
      for (int ns = 0; ns < 2; ns++) {
        int col = by*64 + wn + ns*16 + l15;
        for (int r = 0; r < 4; r++)
          Wf[((long)h*256 + m + r) * 256 + col] = f2bf(acc[ms][ns][r]);
      }
    }
  } else {
    const int idx = gb - 848;
    const int h = idx >> 4, ng = idx & 15;
    const int ni = tid & 15, di = tid >> 4;
    const int n = ng * 16 + ni;
    float acc = 0.f;
    for (int j = 0; j < 16; j++) {
      int d = di * 16 + j;
      acc += WV_b[h*256 + d] * WO_w[n * 2048 + d*8 + h];
    }
    cb_s[ni][di] = acc;
    __syncthreads();
    if (tid < 16) {
      float s = 0.f;
      for (int d2 = 0; d2 < 16; d2++) s += cb_s[tid][d2];
      cbias[h*256 + ng*16 + tid] = s;
    }
  }
}

// ---------------------------------------------------------------------------
// front (1024 blocks), all-bf16 staging (pure short8 copies):
//  [0,512):    Ut GEMM, 256x128 tiles (value re-read factor 8, was 16)
//  [512,768):  K projection (128x64 tiles)
//  [768,1024): Q projection (x log2e)
// ---------------------------------------------------------------------------
__global__ __launch_bounds__(256)
void front(const short* __restrict__ Kb, const short* __restrict__ Qb,
           const short* __restrict__ Vb,
           const short* __restrict__ WKb, const short* __restrict__ WQb,
           const float* __restrict__ WK_b, const float* __restrict__ WQ_b,
           const short* __restrict__ Wf, const float* __restrict__ cbias,
           short* __restrict__ Kp, short* __restrict__ Qp,
           short* __restrict__ Ut) {
  __shared__ __align__(16) short As[256][40];   // 20480 B
  __shared__ __align__(16) short Bs[128][40];   // 10240 B
  const int gb  = blockIdx.x;
  const int tid = threadIdx.x;
  const int wave = tid >> 6, lane = tid & 63;
  const int l15  = lane & 15, quad = lane >> 4;
  const int srow = tid >> 2;          // 0..63
  const int sc8  = (tid & 3) * 8;     // 0,8,16,24

  if (gb < 512) {
    // ---- Ut[b][m][s] = sum_k Wf[m][k]*Vb[b*2048+s][k] + cbias[m]
    const int bx = gb & 7;            // M-tile (256 rows of Wf)
    const int by = gb >> 3;           // N-tile (128 value rows)
    const long Abase = (long)bx * 256;
    const long Bbase = (long)by * 128;

    float4v acc[4][8];                // wave owns 64 m x 128 n
    for (int i = 0; i < 4; i++)
      for (int j = 0; j < 8; j++)
        for (int r = 0; r < 4; r++) acc[i][j][r] = 0.f;

    for (int k0 = 0; k0 < 256; k0 += 32) {
      __syncthreads();
      for (int i = 0; i < 4; i++) {
        int row = srow + i * 64;
        *(short8*)&As[row][sc8] = *(const short8*)(Wf + (Abase + row) * 256 + k0 + sc8);
      }
      for (int i = 0; i < 2; i++) {
        int row = srow + i * 64;
        *(short8*)&Bs[row][sc8] = *(const short8*)(Vb + (Bbase + row) * 256 + k0 + sc8);
      }
      __syncthreads();
      short8 af[4], bfr[8];
      for (int ms = 0; ms < 4; ms++)
        af[ms] = *(const short8*)&As[wave*64 + ms*16 + l15][quad*8];
      for (int ns = 0; ns < 8; ns++)
        bfr[ns] = *(const short8*)&Bs[ns*16 + l15][quad*8];
      for (int ms = 0; ms < 4; ms++)
        for (int ns = 0; ns < 8; ns++)
          acc[ms][ns] = __builtin_amdgcn_mfma_f32_16x16x32_bf16(af[ms], bfr[ns], acc[ms][ns], 0, 0, 0);
    }

    for (int ms = 0; ms < 4; ms++) {
      for (int ns = 0; ns < 8; ns++) {
        int col = (int)Bbase + ns*16 + l15;
        int bidx = col >> 11, scol = col & 2047;
        for (int r = 0; r < 4; r++) {
          long m = Abase + wave*64 + ms*16 + quad*4 + r;
          Ut[((long)bidx * 2048 + m) * 2048 + scol] = f2bf(acc[ms][ns][r] + cbias[m]);
        }
      }
    }
  } else {
    // ---- K/Q projection, 128x64 tile, all-bf16
    const bool isQ = (gb >= 768);
    const int g   = gb - (isQ ? 768 : 512);
    const int bx  = g & 63, by = g >> 6;
    const short* A  = isQ ? Qb  : Kb;
    const short* Bw = isQ ? WQb : WKb;
    const float* bias = isQ ? WQ_b : WK_b;
    short* C = isQ ? Qp : Kp;
    const float oscale = isQ ? 1.44269504f : 1.0f;

    const int wm = (wave & 1) * 64, wn = (wave >> 1) * 32;
    const long Abase = (long)bx * 128;
    const long Bbase = (long)by * 64;

    float4v acc[4][2];
    for (int i = 0; i < 4; i++)
      for (int j = 0; j < 2; j++)
        for (int r = 0; r < 4; r++) acc[i][j][r] = 0.f;

    for (int k0 = 0; k0 < 256; k0 += 32) {
      __syncthreads();
      for (int i = 0; i < 2; i++) {
        int row = srow + i * 64;
        *(short8*)&As[row][sc8] = *(const short8*)(A + (Abase + row) * 256 + k0 + sc8);
      }
      *(short8*)&Bs[srow][sc8] = *(const short8*)(Bw + (Bbase + srow) * 256 + k0 + sc8);
      __syncthreads();
      short8 af[4], bfr[2];
      for (int ms = 0; ms < 4; ms++) af[ms]  = *(const short8*)&As[wm + ms*16 + l15][quad*8];
      for (int ns = 0; ns < 2; ns++) bfr[ns] = *(const short8*)&Bs[wn + ns*16 + l15][quad*8];
      for (int ms = 0; ms < 4; ms++)
        for (int ns = 0; ns < 2; ns++)
          acc[ms][ns] = __builtin_amdgcn_mfma_f32_16x16x32_bf16(af[ms], bfr[ns], acc[ms][ns], 0, 0, 0);
    }

    for (int ms = 0; ms < 4; ms++) {
      int rowl = wm + ms*16 + quad*4;
      for (int ns = 0; ns < 2; ns++) {
        int col = (int)Bbase + wn + ns*16 + l15;
        float bv = bias[col];
        for (int r = 0; r < 4; r++) {
          long row = Abase + rowl + r;
          C[row * 256 + col] = f2bf((acc[ms][ns][r] + bv) * oscale);
        }
      }
    }
  }
}

// ---------------------------------------------------------------------------
// Fused attention — r9 VERBATIM (measured 122.8 us). q-tile 128, no online
// max (|S| <= ~11 -> exact), Qp pre-scaled by log2(e), double-buffered Pt,
// ONE barrier per s-iter. Grid 512; h = id%8 (XCD head locality for Ut).
// Epilogue: normalize, store fp16 per-head partial (plain stores).
// ---------------------------------------------------------------------------
__global__ __launch_bounds__(256, 2)
void attn_kernel(const short* __restrict__ Kp, const short* __restrict__ Qp,
                 const short* __restrict__ Ut, _Float16* __restrict__ partial) {
  __shared__ __align__(16) short Pt[2][128][136];
  __shared__ __align__(16) float psum[128][4];

  const int tid  = threadIdx.x;
  const int wave = tid >> 6, lane = tid & 63;
  const int l15  = lane & 15, quad = lane >> 4;

  const int L  = blockIdx.x;
  const int h  = L & 7;
  const int b  = (L >> 3) & 3;
  const int q0 = (L >> 5) * 128;

  const short* Kbh = Kp + (long)b * T * DM + h * DK;
  const short* Qbh = Qp + (long)b * T * DM + h * DK;
  const short* Ubh = Ut + ((long)b * 2048 + h * 256) * 2048;

  float4v acc[4][8];
  for (int i = 0; i < 4; i++)
    for (int j = 0; j < 8; j++)
      for (int r = 0; r < 4; r++) acc[i][j][r] = 0.f;

  float ps[8];
  for (int i = 0; i < 8; i++) ps[i] = 0.f;

  short8 qf[8];
  for (int qs = 0; qs < 8; qs++)
    qf[qs] = *(const short8*)(Qbh + (long)(q0 + qs*16 + l15) * DM + quad*8);

  auto computeSt = [&](int s0, int buf) {
    for (int ss = 0; ss < 2; ss++) {
      short8 kf = *(const short8*)(Kbh + (long)(s0 + wave*32 + ss*16 + l15) * DM + quad*8);
      for (int qs = 0; qs < 8; qs++) {
        float4v z = {0.f, 0.f, 0.f, 0.f};
        float4v st = __builtin_amdgcn_mfma_f32_16x16x32_bf16(kf, qf[qs], z, 0, 0, 0);
        float p0 = fexp2(st[0]), p1 = fexp2(st[1]);
        float p2 = fexp2(st[2]), p3 = fexp2(st[3]);
        ps[qs] += (p0 + p1) + (p2 + p3);
        uint2v pb; pb[0] = pk2(p0, p1); pb[1] = pk2(p2, p3);
        *(uint2v*)&Pt[buf][qs*16 + l15][wave*32 + ss*16 + quad*4] = pb;
      }
    }
  };

  computeSt(0, 0);

  for (int it = 0; it < T / 128; it++) {
    const int buf = it & 1;
    const int s0  = it * 128;
    __syncthreads();
    if (it < T / 128 - 1) computeSt(s0 + 128, buf ^ 1);
    for (int ks = 0; ks < 4; ks++) {
      short8 pf[8];
      for (int ns = 0; ns < 8; ns++)
        pf[ns] = *(const short8*)&Pt[buf][ns*16 + l15][ks*32 + quad*8];
      for (int ms = 0; ms < 4; ms++) {
        short8 vf = *(const short8*)(Ubh + (long)(wave*64 + ms*16 + l15) * 2048
                                     + s0 + ks*32 + quad*8);
        for (int ns = 0; ns < 8; ns++)
          acc[ms][ns] = __builtin_amdgcn_mfma_f32_16x16x32_bf16(vf, pf[ns], acc[ms][ns], 0, 0, 0);
      }
    }
  }

  for (int qs = 0; qs < 8; qs++) {
    ps[qs] += __shfl_xor(ps[qs], 16, 64);
    ps[qs] += __shfl_xor(ps[qs], 32, 64);
  }
  if (lane < 16)
    for (int qs = 0; qs < 8; qs++) psum[qs*16 + lane][wave] = ps[qs];
  __syncthreads();

  for (int ns = 0; ns < 8; ns++) {
    float4v sv = *(const float4v*)&psum[ns*16 + l15][0];
    float rl = 1.0f / (sv[0] + sv[1] + sv[2] + sv[3]);
    long pbase = ((long)h * 8192 + b * T + q0 + ns*16 + l15) * 256;
    for (int ms = 0; ms < 4; ms++) {
      int ncol = wave*64 + ms*16 + quad*4;
      half4 hv;
      for (int r = 0; r < 4; r++) hv[r] = (_Float16)(acc[ms][ns][r] * rl);
      *(half4*)(partial + pbase + ncol) = hv;
    }
  }
}

// ---------------------------------------------------------------------------
// out[row][n] = WO_b[n] + sum_h partial[h][row][n]
// ---------------------------------------------------------------------------
__global__ void reduce_out(const _Float16* __restrict__ partial,
                           const float* __restrict__ WO_b,
                           float* __restrict__ out) {
  const long HP = 8192L * 256;
  long i4 = ((long)blockIdx.x * 256 + threadIdx.x) * 4;
  float4v o = *(const float4v*)(WO_b + (i4 & 255));
  for (int h = 0; h < 8; h++) {
    half4 hv = *(const half4*)(partial + h * HP + i4);
    for (int r = 0; r < 4; r++) o[r] += (float)hv[r];
  }
  *(float4v*)(out + i4) = o;
}

// ---------------------------------------------------------------------------
extern "C" void kernel_launch(void* const* d_in, const int* in_sizes, int n_in,
                              void* d_out, int out_size, void* d_ws, size_t ws_size,
                              hipStream_t stream) {
  const float* key_x   = (const float*)d_in[0];
  const float* query_x = (const float*)d_in[1];
  const float* value_x = (const float*)d_in[2];
  const float* WK_w = (const float*)d_in[4];
  const float* WK_b = (const float*)d_in[5];
  const float* WQ_w = (const float*)d_in[6];
  const float* WQ_b = (const float*)d_in[7];
  const float* WV_w = (const float*)d_in[8];
  const float* WV_b = (const float*)d_in[9];
  const float* WO_w = (const float*)d_in[10];
  const float* WO_b = (const float*)d_in[11];

  char* ws = (char*)d_ws;
  short*     Kp    = (short*)(ws);                  //  4 MB  [8192][256] bf16
  short*     Qp    = (short*)(ws + (4u  << 20));    //  4 MB  (x log2e)
  short*     Ut    = (short*)(ws + (8u  << 20));    // 32 MB  [4][2048][2048] bf16
  short*     Wf    = (short*)(ws + (40u << 20));    //  1 MB  [2048][256] bf16
  float*     cbias = (float*)(ws + (41u << 20));    //  8 KB  [8][256] fp32
  // bf16 input copies — DEAD after front; 'part' overlaps them.
  short*     Kb    = (short*)(ws + (42u << 20));    //  4 MB  [8192][256]
  short*     Qb    = (short*)(ws + (46u << 20));    //  4 MB
  short*     Vb    = (short*)(ws + (50u << 20));    //  4 MB
  short*     WKb   = (short*)(ws + (54u << 20));    // 128 KB [256][256]
  short*     WQb   = (short*)(ws + (54u << 20) + (128u << 10));
  _Float16*  part  = (_Float16*)(ws + (42u << 20)); // 32 MB  [8][8192][256] fp16
                                                    //   (overlaps Kb..WQb)
  float*     outp  = (float*)d_out;

  prep<<<976, 256, 0, stream>>>(key_x, query_x, value_x, WK_w, WQ_w,
                                WV_w, WV_b, WO_w,
                                Kb, Qb, Vb, WKb, WQb, Wf, cbias);
  front<<<1024, 256, 0, stream>>>(Kb, Qb, Vb, WKb, WQb, WK_b, WQ_b,
                                  Wf, cbias, Kp, Qp, Ut);
  attn_kernel<<<512, 256, 0, stream>>>(Kp, Qp, Ut, part);
  reduce_out<<<2048, 256, 0, stream>>>(part, WO_b, outp);
}

// Round 14
// 297.142 us; speedup vs baseline: 1.6249x; 1.0051x over previous
//
#include <hip/hip_runtime.h>

typedef __attribute__((ext_vector_type(8))) short short8;
typedef __attribute__((ext_vector_type(4))) short short4v;
typedef __attribute__((ext_vector_type(4))) float float4v;
typedef __attribute__((ext_vector_type(16))) float float16v;
typedef __attribute__((ext_vector_type(4))) unsigned uint4v;
typedef __attribute__((ext_vector_type(2))) unsigned uint2v;
typedef __attribute__((ext_vector_type(4))) _Float16 half4;

constexpr int T  = 2048;
constexpr int DM = 256;
constexpr int DK = 32;

__device__ inline short f2bf(float f) {
  unsigned u = __builtin_bit_cast(unsigned, f);
  u += 0x7fff + ((u >> 16) & 1);            // RNE
  return (short)(u >> 16);
}

__device__ inline unsigned pk2(float a, float b) {
#if __has_builtin(__builtin_amdgcn_cvt_pk_bf16_f32)
  auto r = __builtin_amdgcn_cvt_pk_bf16_f32(a, b);
  return __builtin_bit_cast(unsigned, r);
#else
  unsigned ua = __builtin_bit_cast(unsigned, a);
  ua = (ua + 0x7fff + ((ua >> 16) & 1)) >> 16;
  unsigned ub = __builtin_bit_cast(unsigned, b);
  ub = (ub + 0x7fff + ((ub >> 16) & 1)) >> 16;
  return ua | (ub << 16);
#endif
}

__device__ inline float fexp2(float x) {
#if __has_builtin(__builtin_amdgcn_exp2f)
  return __builtin_amdgcn_exp2f(x);
#else
  return exp2f(x);
#endif
}

// ---------------------------------------------------------------------------
// prep (976 blocks): one-time fp32 -> bf16 conversions + tiny weight algebra.
// (identical to r13)
// ---------------------------------------------------------------------------
__device__ inline void conv_block(const float* __restrict__ src,
                                  short* __restrict__ dst, int blk) {
  const int tid = threadIdx.x;
  for (int j = 0; j < 8; j++) {
    int idx = blk * 8192 + j * 1024 + tid * 4;
    float4v v = *(const float4v*)(src + idx);
    uint2v u; u[0] = pk2(v[0], v[1]); u[1] = pk2(v[2], v[3]);
    *(uint2v*)(dst + idx) = u;
  }
}

__global__ __launch_bounds__(256)
void prep(const float* __restrict__ key_x, const float* __restrict__ query_x,
          const float* __restrict__ value_x,
          const float* __restrict__ WK_w, const float* __restrict__ WQ_w,
          const float* __restrict__ WV_w, const float* __restrict__ WV_b,
          const float* __restrict__ WO_w,
          short* __restrict__ Kb, short* __restrict__ Qb, short* __restrict__ Vb,
          short* __restrict__ WKb, short* __restrict__ WQb,
          short* __restrict__ Wf, float* __restrict__ cbias) {
  __shared__ __align__(16) short As[128][40];
  __shared__ __align__(16) short Bs[128][40];
  __shared__ float cb_s[16][17];
  const int gb  = blockIdx.x;
  const int tid = threadIdx.x;

  if (gb < 256) {
    conv_block(key_x, Kb, gb);
  } else if (gb < 512) {
    conv_block(query_x, Qb, gb - 256);
  } else if (gb < 768) {
    conv_block(value_x, Vb, gb - 512);
  } else if (gb < 776) {
    conv_block(WK_w, WKb, gb - 768);
  } else if (gb < 784) {
    conv_block(WQ_w, WQb, gb - 776);
  } else if (gb < 848) {
    const int w  = gb - 784;
    const int h  = w >> 3;
    const int bx = (w >> 2) & 1;
    const int by = w & 3;
    const int wave = tid >> 6, lane = tid & 63;
    const int l15  = lane & 15, quad = lane >> 4;
    const int wm   = (wave & 1) * 64, wn = (wave >> 1) * 32;
    const int srow = tid >> 2, sc8 = (tid & 3) * 8;

    float4v acc[4][2];
    for (int i = 0; i < 4; i++)
      for (int j = 0; j < 2; j++)
        for (int r = 0; r < 4; r++) acc[i][j][r] = 0.f;

    for (int d0 = 0; d0 < 256; d0 += 32) {
      __syncthreads();
      for (int i = 0; i < 2; i++) {
        int row = srow + i * 64;
        for (int j = 0; j < 8; j++)
          As[row][sc8 + j] = f2bf(WO_w[(bx*128 + row) * 2048 + (d0 + sc8 + j) * 8 + h]);
      }
      for (int j = 0; j < 8; j++)
        Bs[srow][sc8 + j] = f2bf(WV_w[((h*256) + d0 + sc8 + j) * 256 + by*64 + srow]);
      __syncthreads();
      short8 af[4], bfr[2];
      for (int ms = 0; ms < 4; ms++) af[ms]  = *(const short8*)&As[wm + ms*16 + l15][quad*8];
      for (int ns = 0; ns < 2; ns++) bfr[ns] = *(const short8*)&Bs[wn + ns*16 + l15][quad*8];
      for (int ms = 0; ms < 4; ms++)
        for (int ns = 0; ns < 2; ns++)
          acc[ms][ns] = __builtin_amdgcn_mfma_f32_16x16x32_bf16(af[ms], bfr[ns], acc[ms][ns], 0, 0, 0);
    }
    for (int ms = 0; ms < 4; ms++) {
      int m = bx*128 + wm + ms*16 + quad*4;
      for (int ns = 0; ns < 2; ns++) {
        int col = by*64 + wn + ns*16 + l15;
        for (int r = 0; r < 4; r++)
          Wf[((long)h*256 + m + r) * 256 + col] = f2bf(acc[ms][ns][r]);
      }
    }
  } else {
    const int idx = gb - 848;
    const int h = idx >> 4, ng = idx & 15;
    const int ni = tid & 15, di = tid >> 4;
    const int n = ng * 16 + ni;
    float acc = 0.f;
    for (int j = 0; j < 16; j++) {
      int d = di * 16 + j;
      acc += WV_b[h*256 + d] * WO_w[n * 2048 + d*8 + h];
    }
    cb_s[ni][di] = acc;
    __syncthreads();
    if (tid < 16) {
      float s = 0.f;
      for (int d2 = 0; d2 < 16; d2++) s += cb_s[tid][d2];
      cbias[h*256 + ng*16 + tid] = s;
    }
  }
}

// ---------------------------------------------------------------------------
// front (1024 blocks), all-bf16 staging — identical to r13.
// ---------------------------------------------------------------------------
__global__ __launch_bounds__(256)
void front(const short* __restrict__ Kb, const short* __restrict__ Qb,
           const short* __restrict__ Vb,
           const short* __restrict__ WKb, const short* __restrict__ WQb,
           const float* __restrict__ WK_b, const float* __restrict__ WQ_b,
           const short* __restrict__ Wf, const float* __restrict__ cbias,
           short* __restrict__ Kp, short* __restrict__ Qp,
           short* __restrict__ Ut) {
  __shared__ __align__(16) short As[256][40];
  __shared__ __align__(16) short Bs[128][40];
  const int gb  = blockIdx.x;
  const int tid = threadIdx.x;
  const int wave = tid >> 6, lane = tid & 63;
  const int l15  = lane & 15, quad = lane >> 4;
  const int srow = tid >> 2;
  const int sc8  = (tid & 3) * 8;

  if (gb < 512) {
    const int bx = gb & 7;
    const int by = gb >> 3;
    const long Abase = (long)bx * 256;
    const long Bbase = (long)by * 128;

    float4v acc[4][8];
    for (int i = 0; i < 4; i++)
      for (int j = 0; j < 8; j++)
        for (int r = 0; r < 4; r++) acc[i][j][r] = 0.f;

    for (int k0 = 0; k0 < 256; k0 += 32) {
      __syncthreads();
      for (int i = 0; i < 4; i++) {
        int row = srow + i * 64;
        *(short8*)&As[row][sc8] = *(const short8*)(Wf + (Abase + row) * 256 + k0 + sc8);
      }
      for (int i = 0; i < 2; i++) {
        int row = srow + i * 64;
        *(short8*)&Bs[row][sc8] = *(const short8*)(Vb + (Bbase + row) * 256 + k0 + sc8);
      }
      __syncthreads();
      short8 af[4], bfr[8];
      for (int ms = 0; ms < 4; ms++)
        af[ms] = *(const short8*)&As[wave*64 + ms*16 + l15][quad*8];
      for (int ns = 0; ns < 8; ns++)
        bfr[ns] = *(const short8*)&Bs[ns*16 + l15][quad*8];
      for (int ms = 0; ms < 4; ms++)
        for (int ns = 0; ns < 8; ns++)
          acc[ms][ns] = __builtin_amdgcn_mfma_f32_16x16x32_bf16(af[ms], bfr[ns], acc[ms][ns], 0, 0, 0);
    }

    for (int ms = 0; ms < 4; ms++) {
      for (int ns = 0; ns < 8; ns++) {
        int col = (int)Bbase + ns*16 + l15;
        int bidx = col >> 11, scol = col & 2047;
        for (int r = 0; r < 4; r++) {
          long m = Abase + wave*64 + ms*16 + quad*4 + r;
          Ut[((long)bidx * 2048 + m) * 2048 + scol] = f2bf(acc[ms][ns][r] + cbias[m]);
        }
      }
    }
  } else {
    const bool isQ = (gb >= 768);
    const int g   = gb - (isQ ? 768 : 512);
    const int bx  = g & 63, by = g >> 6;
    const short* A  = isQ ? Qb  : Kb;
    const short* Bw = isQ ? WQb : WKb;
    const float* bias = isQ ? WQ_b : WK_b;
    short* C = isQ ? Qp : Kp;
    const float oscale = isQ ? 1.44269504f : 1.0f;

    const int wm = (wave & 1) * 64, wn = (wave >> 1) * 32;
    const long Abase = (long)bx * 128;
    const long Bbase = (long)by * 64;

    float4v acc[4][2];
    for (int i = 0; i < 4; i++)
      for (int j = 0; j < 2; j++)
        for (int r = 0; r < 4; r++) acc[i][j][r] = 0.f;

    for (int k0 = 0; k0 < 256; k0 += 32) {
      __syncthreads();
      for (int i = 0; i < 2; i++) {
        int row = srow + i * 64;
        *(short8*)&As[row][sc8] = *(const short8*)(A + (Abase + row) * 256 + k0 + sc8);
      }
      *(short8*)&Bs[srow][sc8] = *(const short8*)(Bw + (Bbase + srow) * 256 + k0 + sc8);
      __syncthreads();
      short8 af[4], bfr[2];
      for (int ms = 0; ms < 4; ms++) af[ms]  = *(const short8*)&As[wm + ms*16 + l15][quad*8];
      for (int ns = 0; ns < 2; ns++) bfr[ns] = *(const short8*)&Bs[wn + ns*16 + l15][quad*8];
      for (int ms = 0; ms < 4; ms++)
        for (int ns = 0; ns < 2; ns++)
          acc[ms][ns] = __builtin_amdgcn_mfma_f32_16x16x32_bf16(af[ms], bfr[ns], acc[ms][ns], 0, 0, 0);
    }

    for (int ms = 0; ms < 4; ms++) {
      int rowl = wm + ms*16 + quad*4;
      for (int ns = 0; ns < 2; ns++) {
        int col = (int)Bbase + wn + ns*16 + l15;
        float bv = bias[col];
        for (int r = 0; r < 4; r++) {
          long row = Abase + rowl + r;
          C[row * 256 + col] = f2bf((acc[ms][ns][r] + bv) * oscale);
        }
      }
    }
  }
}

// ---------------------------------------------------------------------------
// Fused attention — r9 structure, PV switched to 32x32x16 MFMA:
//  * 64 MFMA/iter/wave (was 128), 4096 FLOP/cyc pipe rate (was 3378)
//  * acc = 2x4 tiles x 16 regs = 128 AGPR (unchanged footprint)
//  * Pt pad 136 -> 138 shorts (69-dword odd stride: q=lane&31 reads hit 32
//    distinct banks; <=2-way everywhere)
//  * A/B fragment layouts extrapolated from verified 16x16 symmetry:
//    A[m=lane&31][k=(lane>>5)*8+j]; C/D verified (m74/m101).
// St stays 16x16x32 (dk=32 = one K-step). Everything else r9-verbatim.
// ---------------------------------------------------------------------------
__global__ __launch_bounds__(256, 2)
void attn_kernel(const short* __restrict__ Kp, const short* __restrict__ Qp,
                 const short* __restrict__ Ut, _Float16* __restrict__ partial) {
  __shared__ __align__(16) short Pt[2][128][138];
  __shared__ __align__(16) float psum[128][4];

  const int tid  = threadIdx.x;
  const int wave = tid >> 6, lane = tid & 63;
  const int l15  = lane & 15, quad = lane >> 4;
  const int l31  = lane & 31, half = lane >> 5;

  const int L  = blockIdx.x;
  const int h  = L & 7;
  const int b  = (L >> 3) & 3;
  const int q0 = (L >> 5) * 128;

  const short* Kbh = Kp + (long)b * T * DM + h * DK;
  const short* Qbh = Qp + (long)b * T * DM + h * DK;
  const short* Ubh = Ut + ((long)b * 2048 + h * 256) * 2048;

  float16v acc[2][4];                 // [dt][qt] 32x32 tiles = 128 AGPR
  for (int i = 0; i < 2; i++)
    for (int j = 0; j < 4; j++)
      for (int r = 0; r < 16; r++) acc[i][j][r] = 0.f;

  float ps[8];
  for (int i = 0; i < 8; i++) ps[i] = 0.f;

  short8 qf[8];
  for (int qs = 0; qs < 8; qs++)
    qf[qs] = *(const short8*)(Qbh + (long)(q0 + qs*16 + l15) * DM + quad*8);

  auto computeSt = [&](int s0, int buf) {
    for (int ss = 0; ss < 2; ss++) {
      short8 kf = *(const short8*)(Kbh + (long)(s0 + wave*32 + ss*16 + l15) * DM + quad*8);
      for (int qs = 0; qs < 8; qs++) {
        float4v z = {0.f, 0.f, 0.f, 0.f};
        float4v st = __builtin_amdgcn_mfma_f32_16x16x32_bf16(kf, qf[qs], z, 0, 0, 0);
        float p0 = fexp2(st[0]), p1 = fexp2(st[1]);
        float p2 = fexp2(st[2]), p3 = fexp2(st[3]);
        ps[qs] += (p0 + p1) + (p2 + p3);
        uint2v pb; pb[0] = pk2(p0, p1); pb[1] = pk2(p2, p3);
        *(uint2v*)&Pt[buf][qs*16 + l15][wave*32 + ss*16 + quad*4] = pb;
      }
    }
  };

  computeSt(0, 0);

  for (int it = 0; it < T / 128; it++) {
    const int buf = it & 1;
    const int s0  = it * 128;
    __syncthreads();
    if (it < T / 128 - 1) computeSt(s0 + 128, buf ^ 1);
    // PV: D[d,q] += Ut[d,s] * P^T[s,q], 32x32x16, 8 K-steps over s=128
    for (int ks = 0; ks < 8; ks++) {
      short8 pf[4];
      for (int qt = 0; qt < 4; qt++)
        pf[qt] = *(const short8*)&Pt[buf][qt*32 + l31][ks*16 + half*8];
      for (int dt = 0; dt < 2; dt++) {
        short8 vf = *(const short8*)(Ubh + (long)(wave*64 + dt*32 + l31) * 2048
                                     + s0 + ks*16 + half*8);
        for (int qt = 0; qt < 4; qt++)
          acc[dt][qt] = __builtin_amdgcn_mfma_f32_32x32x16_bf16(vf, pf[qt], acc[dt][qt], 0, 0, 0);
      }
    }
  }

  for (int qs = 0; qs < 8; qs++) {
    ps[qs] += __shfl_xor(ps[qs], 16, 64);
    ps[qs] += __shfl_xor(ps[qs], 32, 64);
  }
  if (lane < 16)
    for (int qs = 0; qs < 8; qs++) psum[qs*16 + lane][wave] = ps[qs];
  __syncthreads();

  // epilogue: q = q0 + qt*32 + l31; d = wave*64 + dt*32 + (reg&3)+8*(reg>>2)+4*half
  for (int qt = 0; qt < 4; qt++) {
    float4v sv = *(const float4v*)&psum[qt*32 + l31][0];
    float rl = 1.0f / (sv[0] + sv[1] + sv[2] + sv[3]);
    long pbase = ((long)h * 8192 + b * T + q0 + qt*32 + l31) * 256;
    for (int dt = 0; dt < 2; dt++) {
      for (int g = 0; g < 4; g++) {
        half4 hv;
        for (int r = 0; r < 4; r++)
          hv[r] = (_Float16)(acc[dt][qt][g*4 + r] * rl);
        int col = wave*64 + dt*32 + g*8 + half*4;
        *(half4*)(partial + pbase + col) = hv;
      }
    }
  }
}

// ---------------------------------------------------------------------------
// out[row][n] = WO_b[n] + sum_h partial[h][row][n]
// ---------------------------------------------------------------------------
__global__ void reduce_out(const _Float16* __restrict__ partial,
                           const float* __restrict__ WO_b,
                           float* __restrict__ out) {
  const long HP = 8192L * 256;
  long i4 = ((long)blockIdx.x * 256 + threadIdx.x) * 4;
  float4v o = *(const float4v*)(WO_b + (i4 & 255));
  for (int h = 0; h < 8; h++) {
    half4 hv = *(const half4*)(partial + h * HP + i4);
    for (int r = 0; r < 4; r++) o[r] += (float)hv[r];
  }
  *(float4v*)(out + i4) = o;
}

// ---------------------------------------------------------------------------
extern "C" void kernel_launch(void* const* d_in, const int* in_sizes, int n_in,
                              void* d_out, int out_size, void* d_ws, size_t ws_size,
                              hipStream_t stream) {
  const float* key_x   = (const float*)d_in[0];
  const float* query_x = (const float*)d_in[1];
  const float* value_x = (const float*)d_in[2];
  const float* WK_w = (const float*)d_in[4];
  const float* WK_b = (const float*)d_in[5];
  const float* WQ_w = (const float*)d_in[6];
  const float* WQ_b = (const float*)d_in[7];
  const float* WV_w = (const float*)d_in[8];
  const float* WV_b = (const float*)d_in[9];
  const float* WO_w = (const float*)d_in[10];
  const float* WO_b = (const float*)d_in[11];

  char* ws = (char*)d_ws;
  short*     Kp    = (short*)(ws);                  //  4 MB  [8192][256] bf16
  short*     Qp    = (short*)(ws + (4u  << 20));    //  4 MB  (x log2e)
  short*     Ut    = (short*)(ws + (8u  << 20));    // 32 MB  [4][2048][2048] bf16
  short*     Wf    = (short*)(ws + (40u << 20));    //  1 MB  [2048][256] bf16
  float*     cbias = (float*)(ws + (41u << 20));    //  8 KB  [8][256] fp32
  short*     Kb    = (short*)(ws + (42u << 20));    //  4 MB  (dead after front)
  short*     Qb    = (short*)(ws + (46u << 20));    //  4 MB
  short*     Vb    = (short*)(ws + (50u << 20));    //  4 MB
  short*     WKb   = (short*)(ws + (54u << 20));    // 128 KB
  short*     WQb   = (short*)(ws + (54u << 20) + (128u << 10));
  _Float16*  part  = (_Float16*)(ws + (42u << 20)); // 32 MB (overlaps Kb..WQb)
  float*     outp  = (float*)d_out;

  prep<<<976, 256, 0, stream>>>(key_x, query_x, value_x, WK_w, WQ_w,
                                WV_w, WV_b, WO_w,
                                Kb, Qb, Vb, WKb, WQb, Wf, cbias);
  front<<<1024, 256, 0, stream>>>(Kb, Qb, Vb, WKb, WQb, WK_b, WQ_b,
                                  Wf, cbias, Kp, Qp, Ut);
  attn_kernel<<<512, 256, 0, stream>>>(Kp, Qp, Ut, part);
  reduce_out<<<2048, 256, 0, stream>>>(part, WO_b, outp);
}